// Round 5
// baseline (224.266 us; speedup 1.0000x reference)
//
#include <hip/hip_runtime.h>
#include <hip/hip_bf16.h>

typedef __attribute__((ext_vector_type(8))) short short8;
typedef __attribute__((ext_vector_type(4))) float f32x4;
typedef __attribute__((ext_vector_type(2))) unsigned uint2v;

#define NN 90
#define FD 32
#define LOG2E 1.4426950408889634f

__device__ inline unsigned short f2bf(float f) {
  return __builtin_bit_cast(unsigned short, __float2bfloat16(f));
}
__device__ inline float bf2f(unsigned short h) {
  unsigned u = ((unsigned)h) << 16;
  return __builtin_bit_cast(float, u);
}
// packed RNE pair: low 16 = bf(a), high 16 = bf(b)  (compiler fuses to v_cvt_pk_bf16_f32)
__device__ inline unsigned pk2(float a, float b) {
  return (unsigned)f2bf(a) | ((unsigned)f2bf(b) << 16);
}
__device__ inline f32x4 mfma16(short8 a, short8 b, f32x4 c) {
  return __builtin_amdgcn_mfma_f32_16x16x32_bf16(a, b, c, 0, 0, 0);
}
// hi/lo bf16 fragment from two preloaded f32x4
__device__ inline void frag_cvt(f32x4 a, f32x4 b, short8& hi, short8& lo) {
  float v[8] = {a[0], a[1], a[2], a[3], b[0], b[1], b[2], b[3]};
  #pragma unroll
  for (int i = 0; i < 8; ++i) {
    unsigned short h = f2bf(v[i]);
    hi[i] = (short)h;
    lo[i] = (short)f2bf(v[i] - bf2f(h));
  }
}

__global__ __launch_bounds__(256, 3) void CAI_35141422416140_kernel(
    const float* __restrict__ sc, const float* __restrict__ fc,
    const float* __restrict__ we, float* __restrict__ out, int nb)
{
  const int b   = blockIdx.x;
  const int tid = threadIdx.x;
  const int w   = tid >> 6;
  const int l   = tid & 63;
  const int lg  = l >> 4;
  const int lj  = l & 15;

  // LDS 50752 B -> 3 blocks/CU (12 waves)
  __shared__ __align__(16) char lds[50752];
  unsigned short* St  = (unsigned short*)(lds + 0);      // [32][104] col-swizzled
  unsigned short* Ft  = (unsigned short*)(lds + 6656);   // [32][104] col-swizzled
  unsigned short* Ghi = (unsigned short*)(lds + 13312);  // [96][40]
  unsigned short* Glo = (unsigned short*)(lds + 20992);  // [96][40]
  unsigned short* E1T = (unsigned short*)(lds + 13312);  // [90][104] overlays G
  unsigned short* ERm = (unsigned short*)(lds + 32032);  // [90][104]

  const float* Sg = sc + (size_t)b * (NN * FD);
  const float* Fg = fc + (size_t)b * (NN * FD);

  // P1: coalesced loads -> transposed bf16 St/Ft; col-swizzle ^((d>>3)&3)<<3
  #pragma unroll
  for (int s = 0; s < 3; ++s) {
    int u  = s * 256 + tid;        // 0..767 = 32 d x 24 n-quads
    int d  = u & 31;
    int n0 = (u >> 5) * 4;         // 0..92
    int n0s = n0 ^ (((d >> 3) & 3) << 3);
    float sv[4], fv[4];
    #pragma unroll
    for (int r = 0; r < 4; ++r) {
      bool ok = (n0 + r) < NN;
      sv[r] = ok ? Sg[(n0 + r) * FD + d] : 0.f;
      fv[r] = ok ? Fg[(n0 + r) * FD + d] : 0.f;
    }
    uint2v sp = { pk2(sv[0], sv[1]), pk2(sv[2], sv[3]) };
    uint2v fp = { pk2(fv[0], fv[1]), pk2(fv[2], fv[3]) };
    *(uint2v*)&St[d * 104 + n0s] = sp;
    *(uint2v*)&Ft[d * 104 + n0s] = fp;
  }

  // P0: W B-fragments (hi/lo), pre-scaled by log2e (folds exp's mul away)
  short8 Wh[2], Wl[2];
  #pragma unroll
  for (int nt = 0; nt < 2; ++nt) {
    #pragma unroll
    for (int e = 0; e < 8; ++e) {
      float wv = we[(lg * 8 + e) * FD + nt * 16 + lj] * LOG2E;
      unsigned short h = f2bf(wv);
      Wh[nt][e] = (short)h;
      Wl[nt][e] = (short)f2bf(wv - bf2f(h));
    }
  }

  // Prefetch S rows for P3 (raw f32; hoisted above barrier)
  const int nta = (9 * w) / 6, ntb = (9 * w + 8) / 6;
  int rowA = nta * 16 + lj; if (rowA > NN - 1) rowA = NN - 1;
  int rowB = ntb * 16 + lj; if (rowB > NN - 1) rowB = NN - 1;
  f32x4 pa0 = *(const f32x4*)(Sg + rowA * FD + lg * 8);
  f32x4 pa1 = *(const f32x4*)(Sg + rowA * FD + lg * 8 + 4);
  f32x4 pb0 = *(const f32x4*)(Sg + rowB * FD + lg * 8);
  f32x4 pb1 = *(const f32x4*)(Sg + rowB * FD + lg * 8 + 4);

  // P2: G = F*W (split precision), F rows per-lane from global
  #pragma unroll
  for (int rep = 0; rep < 2; ++rep) {
    int mt = w + rep * 4;
    if (mt <= 5) {
      int row = mt * 16 + lj; if (row > NN - 1) row = NN - 1;
      f32x4 f0 = *(const f32x4*)(Fg + row * FD + lg * 8);
      f32x4 f1 = *(const f32x4*)(Fg + row * FD + lg * 8 + 4);
      short8 fh, fl;
      frag_cvt(f0, f1, fh, fl);
      #pragma unroll
      for (int nt = 0; nt < 2; ++nt) {
        f32x4 g = {0.f, 0.f, 0.f, 0.f};
        g = mfma16(fh, Wh[nt], g);
        g = mfma16(fh, Wl[nt], g);
        g = mfma16(fl, Wh[nt], g);
        #pragma unroll
        for (int q = 0; q < 4; ++q) {
          int grow = mt * 16 + lg * 4 + q;
          unsigned short gh = f2bf(g[q]);
          Ghi[grow * 40 + nt * 16 + lj] = gh;
          Glo[grow * 40 + nt * 16 + lj] = f2bf(g[q] - bf2f(gh));
        }
      }
    }
  }
  __syncthreads();

  // P3: dual pass — A[nt,mt] and AT[mt,nt] from the SAME register fragments
  f32x4 a_acc[9], t_acc[9];
  short8 sa_h, sa_l, sb_h, sb_l;
  frag_cvt(pa0, pa1, sa_h, sa_l);
  frag_cvt(pb0, pb1, sb_h, sb_l);
  #pragma unroll
  for (int i = 0; i < 9; ++i) {
    int t6 = 9 * w + i;
    int nt = t6 / 6, mt = t6 % 6;
    short8 sh8 = (nt == nta) ? sa_h : sb_h;
    short8 sl8 = (nt == nta) ? sa_l : sb_l;
    short8 gh8 = *(const short8*)&Ghi[(mt * 16 + lj) * 40 + lg * 8];
    short8 gl8 = *(const short8*)&Glo[(mt * 16 + lj) * 40 + lg * 8];
    f32x4 a = {0.f, 0.f, 0.f, 0.f};
    a = mfma16(sh8, gh8, a);
    a = mfma16(sh8, gl8, a);
    a = mfma16(sl8, gh8, a);
    a_acc[i] = a;
    f32x4 t = {0.f, 0.f, 0.f, 0.f};
    t = mfma16(gh8, sh8, t);
    t = mfma16(gh8, sl8, t);
    t = mfma16(gl8, sh8, t);
    t_acc[i] = t;
  }
  __syncthreads();  // all G reads done; E1T overlay safe

  // P4: exp2 (log2e pre-folded) + packed b64 writes of BOTH layouts
  const unsigned edge_lo = (lg < 3) ? 0xFFFFFFFFu : 0u;  // cols 4lg+{0,1} < 10
  const unsigned edge_hi = (lg < 2) ? 0xFFFFFFFFu : 0u;  // cols 4lg+{2,3} < 10
  #pragma unroll
  for (int i = 0; i < 9; ++i) {
    int t6 = 9 * w + i;
    int nt = t6 / 6, mt = t6 % 6;
    f32x4 a = a_acc[i], t = t_acc[i];
    #pragma unroll
    for (int q = 0; q < 4; ++q) {
      a[q] = __builtin_amdgcn_exp2f(a[q]);
      t[q] = __builtin_amdgcn_exp2f(t[q]);
    }
    unsigned a0 = pk2(a[0], a[1]), a1 = pk2(a[2], a[3]);
    if (nt == 5) { a0 &= edge_lo; a1 &= edge_hi; }
    int rowm = mt * 16 + lj;
    if (rowm < NN) {
      uint2v pk = {a0, a1};
      *(uint2v*)&E1T[rowm * 104 + nt * 16 + lg * 4] = pk;
    }
    unsigned t0 = pk2(t[0], t[1]), t1 = pk2(t[2], t[3]);
    if (mt == 5) { t0 &= edge_lo; t1 &= edge_hi; }
    int rown = nt * 16 + lj;
    if (rown < NN) {
      uint2v pk = {t0, t1};
      *(uint2v*)&ERm[rown * 104 + mt * 16 + lg * 4] = pk;
    }
  }
  __syncthreads();

  const short ONE = (short)0x3F80;  // bf16 1.0
  const short8 ones = {ONE, ONE, ONE, ONE, ONE, ONE, ONE, ONE};
  const size_t ob1 = (size_t)b * (NN * FD);
  const size_t ob2 = (size_t)nb * (NN * FD) + ob1;

  // P5a: cosc[m][d] = sum_n E1T[m][n]*S[n][d] / csum[m]
  {
    f32x4 inv; int curmt = -1;
    #pragma unroll
    for (int i = 0; i < 3; ++i) {
      int t5 = 3 * w + i;
      int mt = t5 >> 1, dt = t5 & 1;
      bool newmt = (mt != curmt);
      int arow = mt * 16 + lj; if (arow > NN - 1) arow = NN - 1;
      int srow = dt * 16 + lj;
      int ssw = ((srow >> 3) & 3) << 3;
      f32x4 o = {0.f, 0.f, 0.f, 0.f};
      f32x4 s4 = {0.f, 0.f, 0.f, 0.f};
      #pragma unroll
      for (int ks = 0; ks < 3; ++ks) {
        short8 af = *(const short8*)&E1T[arow * 104 + ks * 32 + lg * 8];
        short8 bf = *(const short8*)&St [srow * 104 + ((ks * 32 + lg * 8) ^ ssw)];
        o = mfma16(af, bf, o);
        if (newmt) s4 = mfma16(af, ones, s4);
      }
      if (newmt) {
        #pragma unroll
        for (int q = 0; q < 4; ++q) inv[q] = __builtin_amdgcn_rcpf(s4[q]);
        curmt = mt;
      }
      #pragma unroll
      for (int q = 0; q < 4; ++q) {
        int m = mt * 16 + lg * 4 + q;
        if (m < NN) out[ob1 + m * FD + dt * 16 + lj] = o[q] * inv[q];
      }
    }
  }

  // P5b: cofc[n][d] = sum_m ERm[n][m]*F[m][d] / rsum[n]
  {
    f32x4 inv; int curnt = -1;
    #pragma unroll
    for (int i = 0; i < 3; ++i) {
      int t5 = 3 * w + i;
      int ntt = t5 >> 1, dt = t5 & 1;
      bool newnt = (ntt != curnt);
      int arow = ntt * 16 + lj; if (arow > NN - 1) arow = NN - 1;
      int frow = dt * 16 + lj;
      int fsw = ((frow >> 3) & 3) << 3;
      f32x4 o = {0.f, 0.f, 0.f, 0.f};
      f32x4 s4 = {0.f, 0.f, 0.f, 0.f};
      #pragma unroll
      for (int ks = 0; ks < 3; ++ks) {
        short8 af = *(const short8*)&ERm[arow * 104 + ks * 32 + lg * 8];
        short8 bf = *(const short8*)&Ft [frow * 104 + ((ks * 32 + lg * 8) ^ fsw)];
        o = mfma16(af, bf, o);
        if (newnt) s4 = mfma16(af, ones, s4);
      }
      if (newnt) {
        #pragma unroll
        for (int q = 0; q < 4; ++q) inv[q] = __builtin_amdgcn_rcpf(s4[q]);
        curnt = ntt;
      }
      #pragma unroll
      for (int q = 0; q < 4; ++q) {
        int n = ntt * 16 + lg * 4 + q;
        if (n < NN) out[ob2 + n * FD + dt * 16 + lj] = o[q] * inv[q];
      }
    }
  }
}

extern "C" void kernel_launch(void* const* d_in, const int* in_sizes, int n_in,
                              void* d_out, int out_size, void* d_ws, size_t ws_size,
                              hipStream_t stream) {
  const float* sc = (const float*)d_in[0];
  const float* fc = (const float*)d_in[1];
  const float* we = (const float*)d_in[2];
  float* out = (float*)d_out;
  int nb = in_sizes[0] / (NN * FD);  // 8192
  CAI_35141422416140_kernel<<<dim3(nb), dim3(256), 0, stream>>>(sc, fc, we, out, nb);
}

// Round 6
// 196.029 us; speedup vs baseline: 1.1440x; 1.1440x over previous
//
#include <hip/hip_runtime.h>
#include <hip/hip_bf16.h>

typedef __attribute__((ext_vector_type(8))) short short8;
typedef __attribute__((ext_vector_type(4))) float f32x4;
typedef __attribute__((ext_vector_type(2))) unsigned uint2v;

#define NN 90
#define FD 32
#define LOG2E 1.4426950408889634f

__device__ inline unsigned short f2bf(float f) {
  return __builtin_bit_cast(unsigned short, __float2bfloat16(f));
}
__device__ inline float bf2f(unsigned short h) {
  unsigned u = ((unsigned)h) << 16;
  return __builtin_bit_cast(float, u);
}
// packed pair: low16 = bf(a), high16 = bf(b)  (fuses to v_cvt_pk_bf16_f32)
__device__ inline unsigned pk2(float a, float b) {
  return (unsigned)f2bf(a) | ((unsigned)f2bf(b) << 16);
}
__device__ inline f32x4 mfma16(short8 a, short8 b, f32x4 c) {
  return __builtin_amdgcn_mfma_f32_16x16x32_bf16(a, b, c, 0, 0, 0);
}
__device__ inline void frag_cvt(f32x4 a, f32x4 b, short8& hi, short8& lo) {
  float v[8] = {a[0], a[1], a[2], a[3], b[0], b[1], b[2], b[3]};
  #pragma unroll
  for (int i = 0; i < 8; ++i) {
    unsigned short h = f2bf(v[i]);
    hi[i] = (short)h;
    lo[i] = (short)f2bf(v[i] - bf2f(h));
  }
}

// One block = one (batch, mode). mode0: cosc via A = S*G^T. mode1: cofc via A^T = G*S^T.
__global__ __launch_bounds__(256, 6) void CAI_35141422416140_kernel(
    const float* __restrict__ sc, const float* __restrict__ fc,
    const float* __restrict__ we, float* __restrict__ out, int nb)
{
  const int bid   = blockIdx.x;
  const int mode  = bid & 1;
  const int batch = bid >> 1;
  const int tid = threadIdx.x;
  const int w   = tid >> 6;
  const int l   = tid & 63;
  const int lg  = l >> 4;
  const int lj  = l & 15;

  // LDS 25376 B -> 6 blocks/CU (24 waves/CU)
  __shared__ __align__(16) char lds[25376];
  unsigned short* Tt  = (unsigned short*)(lds + 0);      // [32][104] staged transpose
  unsigned short* Ghi = (unsigned short*)(lds + 6656);   // [96][40]
  unsigned short* Glo = (unsigned short*)(lds + 14336);  // [96][40]
  unsigned short* E   = (unsigned short*)(lds + 6656);   // [90][104] overlays G after P3

  const float* Sg = sc + (size_t)batch * (NN * FD);
  const float* Fg = fc + (size_t)batch * (NN * FD);
  const float* Xg = mode ? Fg : Sg;   // tensor staged transposed (P5 B-operand)

  // P1: coalesced scalar loads -> transposed bf16 Tt (zero-padded n>=90)
  #pragma unroll
  for (int s = 0; s < 3; ++s) {
    int u  = s * 256 + tid;        // 0..767 = 32 d x 24 n-quads
    int d  = u & 31;
    int n0 = (u >> 5) * 4;         // 0..92
    float v[4];
    #pragma unroll
    for (int r = 0; r < 4; ++r) {
      bool ok = (n0 + r) < NN;
      v[r] = ok ? Xg[(n0 + r) * FD + d] : 0.f;
    }
    uint2v p = { pk2(v[0], v[1]), pk2(v[2], v[3]) };
    *(uint2v*)&Tt[d * 104 + n0] = p;
  }

  // P0: W B-fragments (hi/lo), pre-scaled by log2e
  short8 Wh[2], Wl[2];
  #pragma unroll
  for (int nt = 0; nt < 2; ++nt) {
    #pragma unroll
    for (int e = 0; e < 8; ++e) {
      float wv = we[(lg * 8 + e) * FD + nt * 16 + lj] * LOG2E;
      unsigned short h = f2bf(wv);
      Wh[nt][e] = (short)h;
      Wl[nt][e] = (short)f2bf(wv - bf2f(h));
    }
  }

  // P2: G = F*W (split precision), 6 tiles over 4 waves
  #pragma unroll
  for (int rep = 0; rep < 2; ++rep) {
    int mt = w + rep * 4;
    if (mt <= 5) {
      int row = mt * 16 + lj; if (row > NN - 1) row = NN - 1;
      f32x4 f0 = *(const f32x4*)(Fg + row * FD + lg * 8);
      f32x4 f1 = *(const f32x4*)(Fg + row * FD + lg * 8 + 4);
      short8 fh, fl;
      frag_cvt(f0, f1, fh, fl);
      #pragma unroll
      for (int nt = 0; nt < 2; ++nt) {
        f32x4 g = {0.f, 0.f, 0.f, 0.f};
        g = mfma16(fh, Wh[nt], g);
        g = mfma16(fh, Wl[nt], g);
        g = mfma16(fl, Wh[nt], g);
        #pragma unroll
        for (int q = 0; q < 4; ++q) {
          int grow = mt * 16 + lg * 4 + q;
          unsigned short gh = f2bf(g[q]);
          Ghi[grow * 40 + nt * 16 + lj] = gh;
          Glo[grow * 40 + nt * 16 + lj] = f2bf(g[q] - bf2f(gh));
        }
      }
    }
  }
  __syncthreads();

  // P3: 9 tiles/wave. mode0: acc = S*G^T tile; mode1: acc = G*S^T tile.
  // S-row fragment keyed by nt (slow index, 2 reloads/wave); G rows from LDS.
  f32x4 acc[9];
  {
    short8 sh8, sl8;
    int cur_nt = -1;
    if (mode == 0) {
      #pragma unroll
      for (int i = 0; i < 9; ++i) {
        int t6 = 9 * w + i;
        int nt = t6 / 6, mt = t6 % 6;
        if (nt != cur_nt) {
          int row = nt * 16 + lj; if (row > NN - 1) row = NN - 1;
          f32x4 s0 = *(const f32x4*)(Sg + row * FD + lg * 8);
          f32x4 s1 = *(const f32x4*)(Sg + row * FD + lg * 8 + 4);
          frag_cvt(s0, s1, sh8, sl8);
          cur_nt = nt;
        }
        short8 gh8 = *(const short8*)&Ghi[(mt * 16 + lj) * 40 + lg * 8];
        short8 gl8 = *(const short8*)&Glo[(mt * 16 + lj) * 40 + lg * 8];
        f32x4 a = {0.f, 0.f, 0.f, 0.f};
        a = mfma16(sh8, gh8, a);
        a = mfma16(sh8, gl8, a);
        a = mfma16(sl8, gh8, a);
        acc[i] = a;
      }
    } else {
      #pragma unroll
      for (int i = 0; i < 9; ++i) {
        int t6 = 9 * w + i;
        int nt = t6 / 6, mt = t6 % 6;
        if (nt != cur_nt) {
          int row = nt * 16 + lj; if (row > NN - 1) row = NN - 1;
          f32x4 s0 = *(const f32x4*)(Sg + row * FD + lg * 8);
          f32x4 s1 = *(const f32x4*)(Sg + row * FD + lg * 8 + 4);
          frag_cvt(s0, s1, sh8, sl8);
          cur_nt = nt;
        }
        short8 gh8 = *(const short8*)&Ghi[(mt * 16 + lj) * 40 + lg * 8];
        short8 gl8 = *(const short8*)&Glo[(mt * 16 + lj) * 40 + lg * 8];
        f32x4 a = {0.f, 0.f, 0.f, 0.f};
        a = mfma16(gh8, sh8, a);
        a = mfma16(gh8, sl8, a);
        a = mfma16(gl8, sh8, a);
        acc[i] = a;
      }
    }
  }
  __syncthreads();  // all G reads done; E overlay safe

  // P4: exp2 + packed b64 E writes.
  // mode0: E[m = mt*16+lj][n = nt*16+lg*4+q]; mode1: E[n = nt*16+lj][m = mt*16+lg*4+q]
  const unsigned edge_lo = (lg < 3) ? 0xFFFFFFFFu : 0u;  // block-5 cols 4lg+{0,1} < 10
  const unsigned edge_hi = (lg < 2) ? 0xFFFFFFFFu : 0u;  // block-5 cols 4lg+{2,3} < 10
  #pragma unroll
  for (int i = 0; i < 9; ++i) {
    int t6 = 9 * w + i;
    int nt = t6 / 6, mt = t6 % 6;
    f32x4 a = acc[i];
    #pragma unroll
    for (int q = 0; q < 4; ++q) a[q] = __builtin_amdgcn_exp2f(a[q]);
    unsigned u0 = pk2(a[0], a[1]), u1 = pk2(a[2], a[3]);
    int colblk = mode ? mt : nt;
    int row_p  = (mode ? nt : mt) * 16 + lj;
    if (colblk == 5) { u0 &= edge_lo; u1 &= edge_hi; }
    if (row_p < NN) {
      uint2v pk = {u0, u1};
      *(uint2v*)&E[row_p * 104 + colblk * 16 + lg * 4] = pk;
    }
  }
  __syncthreads();

  // P5: out[row][d] = sum_k E[row][k]*Tt[d][k] / rowsum;  3 tiles/wave
  const short ONE = (short)0x3F80;  // bf16 1.0
  const short8 ones = {ONE, ONE, ONE, ONE, ONE, ONE, ONE, ONE};
  const size_t obase = (size_t)batch * (NN * FD)
                     + (mode ? (size_t)nb * (NN * FD) : (size_t)0);
  {
    f32x4 inv; int currb = -1;
    #pragma unroll
    for (int i = 0; i < 3; ++i) {
      int t5 = 3 * w + i;
      int rb = t5 >> 1, dt = t5 & 1;
      bool newrb = (rb != currb);
      int arow = rb * 16 + lj; if (arow > NN - 1) arow = NN - 1;
      f32x4 o  = {0.f, 0.f, 0.f, 0.f};
      f32x4 s4 = {0.f, 0.f, 0.f, 0.f};
      #pragma unroll
      for (int ks = 0; ks < 3; ++ks) {
        short8 af = *(const short8*)&E [arow * 104 + ks * 32 + lg * 8];
        short8 bf = *(const short8*)&Tt[(dt * 16 + lj) * 104 + ks * 32 + lg * 8];
        o = mfma16(af, bf, o);
        if (newrb) s4 = mfma16(af, ones, s4);
      }
      if (newrb) {
        #pragma unroll
        for (int q = 0; q < 4; ++q) inv[q] = __builtin_amdgcn_rcpf(s4[q]);
        currb = rb;
      }
      #pragma unroll
      for (int q = 0; q < 4; ++q) {
        int row = rb * 16 + lg * 4 + q;
        if (row < NN) out[obase + row * FD + dt * 16 + lj] = o[q] * inv[q];
      }
    }
  }
}

extern "C" void kernel_launch(void* const* d_in, const int* in_sizes, int n_in,
                              void* d_out, int out_size, void* d_ws, size_t ws_size,
                              hipStream_t stream) {
  const float* sc = (const float*)d_in[0];
  const float* fc = (const float*)d_in[1];
  const float* we = (const float*)d_in[2];
  float* out = (float*)d_out;
  int nb = in_sizes[0] / (NN * FD);  // 8192
  CAI_35141422416140_kernel<<<dim3(nb * 2), dim3(256), 0, stream>>>(sc, fc, we, out, nb);
}